// Round 14
// baseline (206.516 us; speedup 1.0000x reference)
//
#include <hip/hip_runtime.h>
#include <hip/hip_fp16.h>

#define NEG_SLOPE 0.2f
#define BK 128            // dst nodes per bucket
#define BK_SHIFT 7
#define CAP 6144          // fixed per-bucket capacity (mean 4224, +29 sigma)
#define CH 8192           // edges per scatter workgroup
#define BMAX 1024         // max buckets (N<=131072)

__device__ __forceinline__ float leaky(float v) { return v > 0.f ? v : NEG_SLOPE * v; }

// ---------------- merged: scatter (blocks < nScat) || gemm1 v9 (rest) ----------------
// gemm1 v9: block = 32 rows; stage the block's ENTIRE 64KB contiguous x-range with
// lane-contiguous 1KB spans walking memory linearly (DRAM page opened once, fully
// consumed) -- the fill/m13 pattern. Compute: 4 waves split K, fp16-packed W1,
// 2-row x 4-j register blocking, one LDS reduce (slab area reused).
__global__ __launch_bounds__(256, 2) void k_scatgemm(
    const int* __restrict__ ei, int E, int ET, int B, int nScat,
    int* __restrict__ gcur, unsigned int* __restrict__ grec,
    const float* __restrict__ x, const float* __restrict__ W1,
    const float* __restrict__ a_s, const float* __restrict__ a_d,
    int N, __half* __restrict__ h, float* __restrict__ asv, float* __restrict__ adv) {
  __shared__ __align__(16) char smem[81920];
  const int t = threadIdx.x;

  if (blockIdx.x < nScat) {
    // ================= scatter role (verbatim) =================
    int* hist = (int*)smem;                        // 4KB
    int* base = (int*)(smem + 4096);               // 4KB
    int* cur  = (int*)(smem + 8192);               // 4KB
    int* gb   = (int*)(smem + 12288);              // 4KB
    int* part = (int*)(smem + 16384);              // 1KB
    unsigned int* recs  = (unsigned int*)(smem + 17408);    // 32KB
    unsigned short* bOf = (unsigned short*)(smem + 50176);  // 16KB

    for (int i = t; i < B; i += 256) hist[i] = 0;
    __syncthreads();
    int cbase = blockIdx.x * CH;
    int lim = min(CH, ET - cbase);
    for (int k = t; k < lim; k += 256) {
      int e = cbase + k;
      int d = (e < E) ? ei[E + e] : (e - E);   // self-loops appended
      atomicAdd(&hist[d >> BK_SHIFT], 1);
    }
    __syncthreads();
    {
      int b4 = t * 4, s = 0;
      int v0 = 0, v1 = 0, v2 = 0, v3 = 0;
      if (b4 + 0 < B) v0 = hist[b4 + 0];
      if (b4 + 1 < B) v1 = hist[b4 + 1];
      if (b4 + 2 < B) v2 = hist[b4 + 2];
      if (b4 + 3 < B) v3 = hist[b4 + 3];
      s = v0 + v1 + v2 + v3;
      part[t] = s;
      __syncthreads();
      for (int d = 1; d < 256; d <<= 1) {
        int tv = (t >= d) ? part[t - d] : 0;
        __syncthreads();
        part[t] += tv;
        __syncthreads();
      }
      int run = part[t] - s;
      if (b4 + 0 < B) { base[b4 + 0] = run; cur[b4 + 0] = run; } run += v0;
      if (b4 + 1 < B) { base[b4 + 1] = run; cur[b4 + 1] = run; } run += v1;
      if (b4 + 2 < B) { base[b4 + 2] = run; cur[b4 + 2] = run; } run += v2;
      if (b4 + 3 < B) { base[b4 + 3] = run; cur[b4 + 3] = run; } run += v3;
    }
    __syncthreads();
    for (int k = t; k < lim; k += 256) {
      int e = cbase + k;
      int s, d;
      if (e < E) { s = ei[e]; d = ei[E + e]; }
      else       { s = e - E; d = s; }
      int b = d >> BK_SHIFT;
      int r = atomicAdd(&cur[b], 1);
      recs[r] = (unsigned)s | ((unsigned)(d & (BK - 1)) << 17);
      bOf[r] = (unsigned short)b;
    }
    __syncthreads();
    for (int i = t; i < B; i += 256) {
      int cnt = cur[i] - base[i];
      gb[i] = cnt ? atomicAdd(&gcur[i], cnt) : 0;
    }
    __syncthreads();
    for (int p = t; p < lim; p += 256) {
      int b = bOf[p];
      grec[(size_t)b * CAP + gb[b] + (p - base[b])] = recs[p];
    }
    return;
  }

  // ================= gemm1 v9 role =================
  __half* w1p = (__half*)smem;                 // 16KB packed [kk4][quad][dk*4+dj]
  float*  xs  = (float*)(smem + 16384);        // 64KB: 32 rows x 128 f4 (src-swizzled)
  const int tid = t;
  const int w = tid >> 6, l = tid & 63;
  const int nbase = (blockIdx.x - nScat) * 32;

  // pack W1 -> fp16 (one-time; W1 is L2-hot across blocks)
  for (int i = tid; i < 8192; i += 256) {
    float v = W1[i];
    int k = i >> 4, j = i & 15;
    int c = k >> 2, dk = k & 3, qq = j >> 2, dj = j & 3;
    w1p[((c * 4 + qq) << 4) + dk * 4 + dj] = __float2half(v);
  }

  // stage 32 rows = 64KB CONTIGUOUS; wave w covers bytes [w*16KB, +16KB), 16
  // instructions of lane-contiguous 1KB each, walking memory linearly.
  {
    char* lb = (char*)xs;
    const float4* xf4 = (const float4*)x;
#pragma unroll
    for (int i = 0; i < 16; ++i) {
      int f4base = (w * 16 + i) * 64;
      unsigned off = (unsigned)(f4base * 16);
      off = __builtin_amdgcn_readfirstlane(off);
      int idx = f4base + l;
      int r = idx >> 7;                      // row in [0,32), same for all lanes
      int s = idx & 127;                     // f4 slot within row
      int grow = nbase + r; if (grow >= N) grow = N - 1;
      const float4* src = xf4 + (size_t)grow * 128 + (s ^ (r >> 1));  // swz in-span
      __builtin_amdgcn_global_load_lds(
          (const __attribute__((address_space(1))) void*)src,
          (__attribute__((address_space(3))) void*)(lb + off), 16, 0, 0);
    }
  }
  asm volatile("s_waitcnt vmcnt(0)" ::: "memory");
  __syncthreads();

  // compute: wave w owns k4 in [w*32, w*32+32); lane: rp=l>>2 -> rows {2rp,2rp+1}, q=l&3
  const int q = l & 3, rp = l >> 2;
  float acc0[4] = {0.f, 0.f, 0.f, 0.f};
  float acc1[4] = {0.f, 0.f, 0.f, 0.f};
  const float4* xsf4 = (const float4*)xs;
#pragma unroll 8
  for (int c = 0; c < 32; ++c) {
    int k4 = w * 32 + c;
    int slot = k4 ^ rp;                      // swz(r) = r>>1 = rp for both rows
    float4 xv0 = xsf4[(2 * rp) * 128 + slot];
    float4 xv1 = xsf4[(2 * rp + 1) * 128 + slot];
    const __half* wp = w1p + (((k4 << 2) + q) << 4);
    uint4 wa = *(const uint4*)(wp);
    uint4 wb = *(const uint4*)(wp + 8);
#define DK(uf0, uf1, xc0, xc1)                                                  \
    { float2 p0 = __half22float2(*(const __half2*)&(uf0));                      \
      float2 p1 = __half22float2(*(const __half2*)&(uf1));                      \
      acc0[0] = fmaf((xc0), p0.x, acc0[0]); acc0[1] = fmaf((xc0), p0.y, acc0[1]); \
      acc0[2] = fmaf((xc0), p1.x, acc0[2]); acc0[3] = fmaf((xc0), p1.y, acc0[3]); \
      acc1[0] = fmaf((xc1), p0.x, acc1[0]); acc1[1] = fmaf((xc1), p0.y, acc1[1]); \
      acc1[2] = fmaf((xc1), p1.x, acc1[2]); acc1[3] = fmaf((xc1), p1.y, acc1[3]); }
    DK(wa.x, wa.y, xv0.x, xv1.x)
    DK(wa.z, wa.w, xv0.y, xv1.y)
    DK(wb.x, wb.y, xv0.z, xv1.z)
    DK(wb.z, wb.w, xv0.w, xv1.w)
#undef DK
  }
  __syncthreads();

  // cross-wave K reduce via LDS (reuse slab area)
  float* redf = (float*)xs;                  // [4][32][17] floats = 8.7KB
  {
    int n0 = 2 * rp, n1 = 2 * rp + 1;
#pragma unroll
    for (int dj = 0; dj < 4; ++dj) {
      redf[(w * 32 + n0) * 17 + q * 4 + dj] = acc0[dj];
      redf[(w * 32 + n1) * 17 + q * 4 + dj] = acc1[dj];
    }
  }
  __syncthreads();
  {
    int n = tid >> 3, sub = tid & 7, jj = sub * 2;
    float f0 = 0.f, f1 = 0.f;
#pragma unroll
    for (int ww = 0; ww < 4; ++ww) {
      f0 += redf[(ww * 32 + n) * 17 + jj];
      f1 += redf[(ww * 32 + n) * 17 + jj + 1];
    }
    float sp = f0 * a_s[jj] + f1 * a_s[jj + 1];
    float dp = f0 * a_d[jj] + f1 * a_d[jj + 1];
    sp += __shfl_xor(sp, 1); sp += __shfl_xor(sp, 2); sp += __shfl_xor(sp, 4);
    dp += __shfl_xor(dp, 1); dp += __shfl_xor(dp, 2); dp += __shfl_xor(dp, 4);
    int gnode = nbase + n;
    if (gnode < N) {
      __half2 hv = __floats2half2_rn(f0, f1);
      *(__half2*)(h + (size_t)gnode * 16 + jj) = hv;
      if (sub == 0) asv[gnode] = sp;
      if (sub == 1) adv[gnode] = dp;
    }
  }
}

// ---------------- phase D: within-bucket counting sort -> per-dst CSR ----------------
__global__ __launch_bounds__(256) void k_sortbk(const unsigned int* __restrict__ grec,
    const int* __restrict__ gcur, int N, int* __restrict__ csr2,
    int* __restrict__ offs2, int* __restrict__ end2) {
  __shared__ int hist[BK];
  __shared__ int cur[BK];
  __shared__ int sc[BK];
  int b = blockIdx.x;
  int t = threadIdx.x;
  if (t < BK) hist[t] = 0;
  __syncthreads();
  int i0 = b * CAP, cnt = gcur[b];
  for (int i = t; i < cnt; i += 256) atomicAdd(&hist[grec[(size_t)i0 + i] >> 17], 1);
  __syncthreads();
  if (t < BK) sc[t] = hist[t];
  __syncthreads();
  for (int d = 1; d < BK; d <<= 1) {
    int v = (t >= d && t < BK) ? sc[t - d] : 0;
    __syncthreads();
    if (t < BK) sc[t] += v;
    __syncthreads();
  }
  if (t < BK) {
    int excl = sc[t] - hist[t];
    cur[t] = excl;
    int n = (b << BK_SHIFT) + t;
    if (n < N) { offs2[n] = i0 + excl; end2[n] = i0 + excl + hist[t]; }
  }
  __syncthreads();
  for (int i = t; i < cnt; i += 256) {
    unsigned r = grec[(size_t)i0 + i];
    int dl = r >> 17;
    int p = atomicAdd(&cur[dl], 1);
    csr2[(size_t)i0 + p] = r & 0x1FFFF;
  }
}

// ---------------- layer-1 aggregate FUSED with gemm16 ----------------
__global__ __launch_bounds__(256) void k_agg1(const __half* __restrict__ hh,
    const float* __restrict__ asv, const float* __restrict__ adv,
    const int* __restrict__ offs2, const int* __restrict__ end2,
    const int* __restrict__ csr2,
    const float* __restrict__ b1, const float* __restrict__ W2,
    const float* __restrict__ as2, const float* __restrict__ ad2,
    int N, __half* __restrict__ h2, float* __restrict__ asv2,
    float* __restrict__ adv2) {
  int t = threadIdx.x;
  int j = t & 15;
  int n = blockIdx.x * 16 + (t >> 4);
  if (n >= N) return;
  int i0 = offs2[n], i1 = end2[n];
  float adn = adv[n];
  float z = 0.f, acc = 0.f;
  int i = i0;
  for (; i + 4 <= i1; i += 4) {
    int s0 = csr2[i], s1 = csr2[i + 1], s2 = csr2[i + 2], s3 = csr2[i + 3];
    float a0 = asv[s0], a1 = asv[s1], a2 = asv[s2], a3 = asv[s3];
    float h0 = __half2float(hh[(size_t)s0 * 16 + j]);
    float h1 = __half2float(hh[(size_t)s1 * 16 + j]);
    float hv2 = __half2float(hh[(size_t)s2 * 16 + j]);
    float h3 = __half2float(hh[(size_t)s3 * 16 + j]);
    float e0 = __expf(leaky(a0 + adn));
    float e1 = __expf(leaky(a1 + adn));
    float e2 = __expf(leaky(a2 + adn));
    float e3 = __expf(leaky(a3 + adn));
    z += (e0 + e1) + (e2 + e3);
    acc = fmaf(e0, h0, acc);
    acc = fmaf(e1, h1, acc);
    acc = fmaf(e2, hv2, acc);
    acc = fmaf(e3, h3, acc);
  }
  for (; i < i1; ++i) {
    int s = csr2[i];
    float e = __expf(leaky(asv[s] + adn));
    z += e;
    acc = fmaf(e, __half2float(hh[(size_t)s * 16 + j]), acc);
  }
  float o = fmaxf(acc / z + b1[j], 0.f);       // x2 row value, lane j

  float hv = 0.f;
#pragma unroll
  for (int k = 0; k < 16; ++k)
    hv = fmaf(__shfl(o, k, 16), W2[k * 16 + j], hv);

  float sp = hv * as2[j], dp = hv * ad2[j];
#pragma unroll
  for (int m = 1; m < 16; m <<= 1) {
    sp += __shfl_xor(sp, m);
    dp += __shfl_xor(dp, m);
  }
  h2[(size_t)n * 16 + j] = __float2half(hv);
  if (j == 0) asv2[n] = sp;
  if (j == 1) adv2[n] = dp;
}

// ---------------- layer-2 aggregate FUSED with output head ----------------
__global__ __launch_bounds__(256) void k_agg2(const __half* __restrict__ hh,
    const float* __restrict__ asv, const float* __restrict__ adv,
    const int* __restrict__ offs2, const int* __restrict__ end2,
    const int* __restrict__ csr2,
    const float* __restrict__ b2, const float* __restrict__ Wout,
    const float* __restrict__ bout, int N, float* __restrict__ out) {
  int t = threadIdx.x;
  int j = t & 15;
  int n = blockIdx.x * 16 + (t >> 4);
  if (n >= N) return;
  int i0 = offs2[n], i1 = end2[n];
  float adn = adv[n];
  float z = 0.f, acc = 0.f;
  int i = i0;
  for (; i + 4 <= i1; i += 4) {
    int s0 = csr2[i], s1 = csr2[i + 1], s2 = csr2[i + 2], s3 = csr2[i + 3];
    float a0 = asv[s0], a1 = asv[s1], a2 = asv[s2], a3 = asv[s3];
    float h0 = __half2float(hh[(size_t)s0 * 16 + j]);
    float h1 = __half2float(hh[(size_t)s1 * 16 + j]);
    float hv2 = __half2float(hh[(size_t)s2 * 16 + j]);
    float h3 = __half2float(hh[(size_t)s3 * 16 + j]);
    float e0 = __expf(leaky(a0 + adn));
    float e1 = __expf(leaky(a1 + adn));
    float e2 = __expf(leaky(a2 + adn));
    float e3 = __expf(leaky(a3 + adn));
    z += (e0 + e1) + (e2 + e3);
    acc = fmaf(e0, h0, acc);
    acc = fmaf(e1, h1, acc);
    acc = fmaf(e2, hv2, acc);
    acc = fmaf(e3, h3, acc);
  }
  for (; i < i1; ++i) {
    int s = csr2[i];
    float e = __expf(leaky(asv[s] + adn));
    z += e;
    acc = fmaf(e, __half2float(hh[(size_t)s * 16 + j]), acc);
  }
  float gv = fmaxf(acc / z + b2[j], 0.f);

  float lg = bout[j];
#pragma unroll
  for (int k = 0; k < 16; ++k)
    lg = fmaf(__shfl(gv, k, 16), Wout[k * 16 + j], lg);

  float mx = lg;
#pragma unroll
  for (int m = 1; m < 16; m <<= 1) mx = fmaxf(mx, __shfl_xor(mx, m));
  float e = __expf(lg - mx);
  float zs = e;
#pragma unroll
  for (int m = 1; m < 16; m <<= 1) zs += __shfl_xor(zs, m);
  out[(size_t)n * 16 + j] = e / zs;
}

// ---------------- launch ----------------

extern "C" void kernel_launch(void* const* d_in, const int* in_sizes, int n_in,
                              void* d_out, int out_size, void* d_ws, size_t ws_size,
                              hipStream_t stream) {
  const float* x    = (const float*)d_in[0];
  const float* W1   = (const float*)d_in[1];
  const float* as1  = (const float*)d_in[2];
  const float* ad1  = (const float*)d_in[3];
  const float* b1   = (const float*)d_in[4];
  const float* W2   = (const float*)d_in[5];
  const float* as2  = (const float*)d_in[6];
  const float* ad2  = (const float*)d_in[7];
  const float* b2   = (const float*)d_in[8];
  const float* Wout = (const float*)d_in[9];
  const float* bout = (const float*)d_in[10];
  const int*   ei   = (const int*)d_in[11];

  const int N  = in_sizes[0] / 512;
  const int E  = in_sizes[11] / 2;
  const int ET = E + N;
  const int B  = (N + BK - 1) >> BK_SHIFT;
  float* out = (float*)d_out;

  char* w = (char*)d_ws;
  auto alloc = [&](size_t bytes) {
    char* p = w;
    w += (bytes + 255) & ~(size_t)255;
    return p;
  };
  __half* h1  = (__half*)alloc((size_t)N * 16 * 2);
  __half* h2  = (__half*)alloc((size_t)N * 16 * 2);
  float* asv1 = (float*)alloc((size_t)N * 4);
  float* adv1 = (float*)alloc((size_t)N * 4);
  float* asv2 = (float*)alloc((size_t)N * 4);
  float* adv2 = (float*)alloc((size_t)N * 4);
  int* gcur  = (int*)alloc((size_t)B * 4);
  unsigned int* grec = (unsigned int*)alloc((size_t)B * CAP * 4);
  int* csr2  = (int*)alloc((size_t)B * CAP * 4);
  int* offs2 = (int*)alloc((size_t)N * 4);
  int* end2  = (int*)alloc((size_t)N * 4);

  const int nScat  = (ET + CH - 1) / CH;
  const int nTiles = (N + 15) / 16;
  const int NB32   = (N + 31) / 32;

  // scatter || gemm1 in ONE launch (independent DAG stages overlap on CUs)
  hipMemsetAsync(gcur, 0, (size_t)B * 4, stream);
  k_scatgemm<<<nScat + NB32, 256, 0, stream>>>(ei, E, ET, B, nScat, gcur, grec,
                                               x, W1, as1, ad1, N, h1, asv1, adv1);

  // within-bucket counting sort -> per-dst CSR
  k_sortbk<<<B, 256, 0, stream>>>(grec, gcur, N, csr2, offs2, end2);

  // layer-1 aggregate + fused 16x16 projection
  k_agg1<<<nTiles, 256, 0, stream>>>(h1, asv1, adv1, offs2, end2, csr2,
                                     b1, W2, as2, ad2, N, h2, asv2, adv2);

  // layer-2 aggregate + fused output head
  k_agg2<<<nTiles, 256, 0, stream>>>(h2, asv2, adv2, offs2, end2, csr2,
                                     b2, Wout, bout, N, out);
}